// Round 10
// baseline (1610.282 us; speedup 1.0000x reference)
//
#include <hip/hip_runtime.h>

#define N_NODE 50000
#define N_EDGE 400000
#define INF    128

#define FUSED_BLOCKS 1024   // 4 blocks/CU resident at <=128 VGPR, 16 node-groups/block
#define QA_BLOCKS    1024

// 64-row MFMA tiles within type segments (boundaries 10000/20000 are 16-aligned)
#define MT0 157
#define MT1 157
#define MT2 469
#define MTILES 783

typedef __bf16 bf16x8 __attribute__((ext_vector_type(8)));
typedef float  f32x4  __attribute__((ext_vector_type(4)));

__device__ __forceinline__ void seg_decode64(int b, int& ty, int& base, int& nrows) {
  if (b < MT0)          { ty = 0; base = b * 64;                nrows = 10000 - base; }
  else if (b < MT0+MT1) { ty = 1; base = 10000 + (b - MT0)*64;  nrows = 20000 - base; }
  else                  { ty = 2; base = 20000 + (b-MT0-MT1)*64; nrows = 50000 - base; }
  if (nrows > 64) nrows = 64;
}

__device__ __forceinline__ float blo(unsigned u) { return __uint_as_float(u << 16); }
__device__ __forceinline__ float bhi(unsigned u) { return __uint_as_float(u & 0xffff0000u); }
// pack two f32 -> bf16x2 (RNE), lo = even dim, hi = odd dim
__device__ __forceinline__ unsigned bpack(float lo, float hi) {
  unsigned a = __float_as_uint(lo), b = __float_as_uint(hi);
  a = (a + 0x7fffu + ((a >> 16) & 1u)) >> 16;
  b = (b + 0x7fffu + ((b >> 16) & 1u)) & 0xffff0000u;
  return a | b;
}
__device__ __forceinline__ unsigned short b16(float v) {
  unsigned u = __float_as_uint(v);
  return (unsigned short)((u + 0x7fffu + ((u >> 16) & 1u)) >> 16);
}
__device__ __forceinline__ bf16x8 ld_frag(const unsigned short* p) {
  uint4 u = *reinterpret_cast<const uint4*>(p);
  return __builtin_bit_cast(bf16x8, u);
}

// ---- concat features into x (= d_out) + bf16 copy xh, grid-stride --------
__global__ __launch_bounds__(256) void k_concat(const float* __restrict__ dr,
                                                const float* __restrict__ di,
                                                const float* __restrict__ pr,
                                                float* __restrict__ x,
                                                unsigned short* __restrict__ xh) {
  for (int i = blockIdx.x * 256 + threadIdx.x; i < N_NODE * 32; i += 2048 * 256) {
    int row = i >> 5;
    float4 val;
    if (row < 10000)      val = ((const float4*)dr)[i];
    else if (row < 20000) val = ((const float4*)di)[i - 10000*32];
    else                  val = ((const float4*)pr)[i - 20000*32];
    ((float4*)x)[i] = val;
    ((uint2*)xh)[i] = make_uint2(bpack(val.x, val.y), bpack(val.z, val.w));
  }
}

// ---- CSR build -----------------------------------------------------------
__global__ __launch_bounds__(256) void k_count(const int* __restrict__ dst, int* __restrict__ deg) {
  int e = blockIdx.x * 256 + threadIdx.x;
  if (e < N_EDGE) atomicAdd(&deg[dst[e]], 1);
}

__global__ __launch_bounds__(1024) void k_scan(const int* __restrict__ deg,
                                               int* __restrict__ off, int* __restrict__ cur) {
  __shared__ int part[1024];
  int t = threadIdx.x;
  int c0 = t * 49;
  int c1 = c0 + 49; if (c1 > N_NODE) c1 = N_NODE;
  int s = 0;
  for (int i = c0; i < c1; ++i) s += deg[i];
  part[t] = s;
  __syncthreads();
  for (int ofs = 1; ofs < 1024; ofs <<= 1) {
    int v = (t >= ofs) ? part[t - ofs] : 0;
    __syncthreads();
    part[t] += v;
    __syncthreads();
  }
  int run = (t == 0) ? 0 : part[t - 1];
  for (int i = c0; i < c1; ++i) { off[i] = run; cur[i] = run; run += deg[i]; }
  if (t == 1023) off[N_NODE] = part[1023];
}

// writes combined edge record est[p] = (src<<2) | etype
__global__ __launch_bounds__(256) void k_fill(const int* __restrict__ dst,
                                              const int* __restrict__ src,
                                              const int* __restrict__ etp,
                                              int* __restrict__ cur, int* __restrict__ est) {
  int e = blockIdx.x * 256 + threadIdx.x;
  if (e < N_EDGE) {
    int p = atomicAdd(&cur[dst[e]], 1);
    est[p] = (src[e] << 2) | etp[e];
  }
}

// ---- transpose rel_msg: AmT[h][ty][do][di] = rel_msg[h][ty][di][do] ------
__global__ __launch_bounds__(256) void k_trmsg(const float* __restrict__ rm,
                                               float* __restrict__ AmT) {
  int i = blockIdx.x * 256 + threadIdx.x;   // 8192 total
  int di = i & 15, doo = (i >> 4) & 15, ty = (i >> 8) & 3, hh = i >> 10;
  AmT[i] = rm[((hh * 4 + ty) * 16 + di) * 16 + doo];
}

// ---- weight transpose to bf16: WT[(mat*3+ty)*16384 + o*128 + i] ----------
__global__ __launch_bounds__(256) void k_twt(const float* __restrict__ Wk,
                                             const float* __restrict__ Wq,
                                             const float* __restrict__ Wv,
                                             const float* __restrict__ Wa,
                                             unsigned short* __restrict__ WT) {
  int idx = blockIdx.x * 256 + threadIdx.x;
  if (idx >= 196608) return;
  int mt = idx >> 14;            // mat*3+ty
  int within = idx & 16383;
  int o = within >> 7, ii = within & 127;
  int mat = mt / 3, ty = mt % 3;
  const float* W = (mat == 0) ? Wk : (mat == 1) ? Wq : (mat == 2) ? Wv : Wa;
  WT[idx] = b16(W[ty * 16384 + ii * 128 + o]);
}

// ---- typed K/Q/V projection via MFMA; k,v packed interleaved bf16 --------
__global__ __launch_bounds__(256) void k_qkv(const unsigned short* __restrict__ xh,
                                             const unsigned short* __restrict__ WT,
                                             uint2* __restrict__ kvb,
                                             unsigned* __restrict__ qbh) {
  int ty, base, nrows;
  seg_decode64(blockIdx.x, ty, base, nrows);
  int w = threadIdx.x >> 6, l = threadIdx.x & 63;
  int r16 = l & 15, ks = l >> 4;
  int row0 = base + w * 16;
  int wrows = nrows - w * 16;        // valid rows in this wave's 16-row tile

  bf16x8 a[4];
  const unsigned short* xrow = xh + (size_t)(row0 + r16) * 128 + ks * 8;
#pragma unroll
  for (int kk = 0; kk < 4; ++kk) a[kk] = ld_frag(xrow + kk * 32);

  const unsigned short* WK = WT + (size_t)(0 * 3 + ty) * 16384;
  const unsigned short* WQ = WT + (size_t)(1 * 3 + ty) * 16384;
  const unsigned short* WV = WT + (size_t)(2 * 3 + ty) * 16384;

#pragma unroll 1
  for (int ct = 0; ct < 8; ++ct) {
    int o = ct * 16 + r16;
    const unsigned short* bk = WK + (size_t)o * 128 + ks * 8;
    const unsigned short* bq = WQ + (size_t)o * 128 + ks * 8;
    const unsigned short* bv = WV + (size_t)o * 128 + ks * 8;
    f32x4 ak = {0.f,0.f,0.f,0.f}, aq = {0.f,0.f,0.f,0.f}, av = {0.f,0.f,0.f,0.f};
#pragma unroll
    for (int kk = 0; kk < 4; ++kk) {
      bf16x8 fbk = ld_frag(bk + kk * 32);
      bf16x8 fbq = ld_frag(bq + kk * 32);
      bf16x8 fbv = ld_frag(bv + kk * 32);
      ak = __builtin_amdgcn_mfma_f32_16x16x32_bf16(a[kk], fbk, ak, 0, 0, 0);
      aq = __builtin_amdgcn_mfma_f32_16x16x32_bf16(a[kk], fbq, aq, 0, 0, 0);
      av = __builtin_amdgcn_mfma_f32_16x16x32_bf16(a[kk], fbv, av, 0, 0, 0);
    }
#pragma unroll
    for (int r = 0; r < 4; ++r) {
      int rrel = ks * 4 + r;
      float kn = __shfl_xor(ak[r], 1);
      float qn = __shfl_xor(aq[r], 1);
      float vn = __shfl_xor(av[r], 1);
      if (rrel < wrows && (l & 1) == 0) {
        size_t p = (size_t)(row0 + rrel);
        kvb[p * 64 + (o >> 1)] = make_uint2(bpack(ak[r], kn), bpack(av[r], vn));
        qbh[p * 64 + (o >> 1)] = bpack(aq[r], qn);
      }
    }
  }
}

// ---- qa precompute -> GROUP layout: qab[n*64 + ty*16 + m] = uint4 --------
// uint4 packs dims 8m..8m+7 (bf16 pairs) of (pri[h,ty]/4)*(A[h,ty].q[n])
__global__ __launch_bounds__(256) void k_qa(const unsigned* __restrict__ qbh,
                                            const float* __restrict__ rel_att,
                                            const float* __restrict__ pri,
                                            uint4* __restrict__ qab) {
  int w = threadIdx.x >> 6, l = threadIdx.x & 63;
  int h = l >> 3, j = l & 7;
  float4 prh = ((const float4*)pri)[h];
  float prs[4] = { prh.x * 0.25f, prh.y * 0.25f, prh.z * 0.25f, prh.w * 0.25f };
  for (int n = blockIdx.x * 4 + w; n < N_NODE; n += QA_BLOCKS * 4) {
    const uint4* qp = (const uint4*)qbh + (size_t)n * 16 + h * 2;
    uint4 u0 = qp[0], u1 = qp[1];
    float qf[16];
    qf[0]=blo(u0.x); qf[1]=bhi(u0.x); qf[2]=blo(u0.y); qf[3]=bhi(u0.y);
    qf[4]=blo(u0.z); qf[5]=bhi(u0.z); qf[6]=blo(u0.w); qf[7]=bhi(u0.w);
    qf[8]=blo(u1.x); qf[9]=bhi(u1.x); qf[10]=blo(u1.y); qf[11]=bhi(u1.y);
    qf[12]=blo(u1.z); qf[13]=bhi(u1.z); qf[14]=blo(u1.w); qf[15]=bhi(u1.w);
    unsigned pk[4];
#pragma unroll
    for (int ty = 0; ty < 4; ++ty) {
      const float* Ar = rel_att + (((h * 4 + ty) * 16) + 2 * j) * 16;
      float ax = 0.f, ay = 0.f;
#pragma unroll
      for (int o = 0; o < 16; ++o) {
        ax += Ar[o] * qf[o];
        ay += Ar[16 + o] * qf[o];
      }
      pk[ty] = bpack(ax * prs[ty], ay * prs[ty]);
    }
    // lane l covers dim pair P=8h+j; lanes 4m..4m+3 hold pairs of group-lane m
#pragma unroll
    for (int ty = 0; ty < 4; ++ty) {
      unsigned p1 = __shfl(pk[ty], l + 1);
      unsigned p2 = __shfl(pk[ty], l + 2);
      unsigned p3 = __shfl(pk[ty], l + 3);
      if ((l & 3) == 0)
        qab[(size_t)n * 64 + ty * 16 + (l >> 2)] = make_uint4(pk[ty], p1, p2, p3);
    }
  }
}

// ---- fused attention: 16-lane group per node, 4 nodes/wave ---------------
// lane m of group: dims [8m, 8m+8), head h = m>>1. Per edge: 32B kv slice,
// 1 shfl for the head-dot, no-max softmax, 4-ty raw-v accumulation.
// Epilogue: pair-shuffle + AmT matvec in registers (no LDS).
__global__ __launch_bounds__(256, 4) void k_fused(const uint2* __restrict__ kvb,
                                                  const uint4* __restrict__ qab,
                                                  const int* __restrict__ off,
                                                  const int* __restrict__ est,
                                                  const float* __restrict__ AmT,
                                                  unsigned* __restrict__ hbh) {
  int w = threadIdx.x >> 6, l = threadIdx.x & 63;
  int g = l >> 4, m = l & 15;
  int h = m >> 1;
  bool hi = (m & 1);
  const uint4* kv4 = (const uint4*)kvb;

  for (int nb = blockIdx.x * 16 + w * 4; nb < N_NODE; nb += FUSED_BLOCKS * 16) {
    int n = nb + g;
    int o0 = off[n], o1 = off[n + 1];
    uint4 qa0 = qab[(size_t)n * 64 + 0 * 16 + m];
    uint4 qa1 = qab[(size_t)n * 64 + 1 * 16 + m];
    uint4 qa2 = qab[(size_t)n * 64 + 2 * 16 + m];
    uint4 qa3 = qab[(size_t)n * 64 + 3 * 16 + m];

    float ssum = 0.f;
    float2 z = make_float2(0.f, 0.f);
    float2 a00=z,a01=z,a02=z,a03=z;
    float2 a10=z,a11=z,a12=z,a13=z;
    float2 a20=z,a21=z,a22=z,a23=z;
    float2 a30=z,a31=z,a32=z,a33=z;

    for (int b0 = o0; b0 < o1; b0 += 16) {
      int cnt = o1 - b0; if (cnt > 16) cnt = 16;
      int stv = est[b0 + m];               // est padded -> no guard
      int tc = __shfl(stv, g * 16);
      size_t rc = (size_t)(tc >> 2) * 32 + m * 2;
      uint4 c0 = kv4[rc], c1 = kv4[rc + 1];
      for (int i = 0; i < cnt; ++i) {
        int slot = (i + 1 < cnt) ? (i + 1) : i;   // group-uniform
        int tn = __shfl(stv, g * 16 + slot);
        size_t rn = (size_t)(tn >> 2) * 32 + m * 2;
        uint4 d0 = kv4[rn], d1 = kv4[rn + 1];

        int ty = tc & 3;
        uint4 qa = (ty == 0) ? qa0 : (ty == 1) ? qa1 : (ty == 2) ? qa2 : qa3;
        float part = blo(c0.x)*blo(qa.x) + bhi(c0.x)*bhi(qa.x)
                   + blo(c0.z)*blo(qa.y) + bhi(c0.z)*bhi(qa.y)
                   + blo(c1.x)*blo(qa.z) + bhi(c1.x)*bhi(qa.z)
                   + blo(c1.z)*blo(qa.w) + bhi(c1.z)*bhi(qa.w);
        part += __shfl_xor(part, 1);      // partner lane completes the head dot
        float wgt = __expf(part);
        ssum += wgt;
        float w0=(ty==0)?wgt:0.f, w1=(ty==1)?wgt:0.f, w2=(ty==2)?wgt:0.f, w3=(ty==3)?wgt:0.f;
        float v0x=blo(c0.y), v0y=bhi(c0.y), v1x=blo(c0.w), v1y=bhi(c0.w);
        float v2x=blo(c1.y), v2y=bhi(c1.y), v3x=blo(c1.w), v3y=bhi(c1.w);
        a00.x+=w0*v0x; a00.y+=w0*v0y; a01.x+=w0*v1x; a01.y+=w0*v1y;
        a02.x+=w0*v2x; a02.y+=w0*v2y; a03.x+=w0*v3x; a03.y+=w0*v3y;
        a10.x+=w1*v0x; a10.y+=w1*v0y; a11.x+=w1*v1x; a11.y+=w1*v1y;
        a12.x+=w1*v2x; a12.y+=w1*v2y; a13.x+=w1*v3x; a13.y+=w1*v3y;
        a20.x+=w2*v0x; a20.y+=w2*v0y; a21.x+=w2*v1x; a21.y+=w2*v1y;
        a22.x+=w2*v2x; a22.y+=w2*v2y; a23.x+=w2*v3x; a23.y+=w2*v3y;
        a30.x+=w3*v0x; a30.y+=w3*v0y; a31.x+=w3*v1x; a31.y+=w3*v1y;
        a32.x+=w3*v2x; a32.y+=w3*v2y; a33.x+=w3*v3x; a33.y+=w3*v3y;

        tc = tn; c0 = d0; c1 = d1;
      }
    }

    float inv = (ssum > 0.f) ? 1.f / ssum : 0.f;
    int odb = hi ? 8 : 0;
    float out[8] = {0.f,0.f,0.f,0.f,0.f,0.f,0.f,0.f};

#define EPI(TY, B0, B1, B2, B3) { \
    float p0x = __shfl_xor(B0.x,1), p0y = __shfl_xor(B0.y,1); \
    float p1x = __shfl_xor(B1.x,1), p1y = __shfl_xor(B1.y,1); \
    float p2x = __shfl_xor(B2.x,1), p2y = __shfl_xor(B2.y,1); \
    float p3x = __shfl_xor(B3.x,1), p3y = __shfl_xor(B3.y,1); \
    float e0 = hi ? p0x : B0.x, e1 = hi ? p0y : B0.y; \
    float e2 = hi ? p1x : B1.x, e3 = hi ? p1y : B1.y; \
    float e4 = hi ? p2x : B2.x, e5 = hi ? p2y : B2.y; \
    float e6 = hi ? p3x : B3.x, e7 = hi ? p3y : B3.y; \
    float e8  = hi ? B0.x : p0x, e9  = hi ? B0.y : p0y; \
    float e10 = hi ? B1.x : p1x, e11 = hi ? B1.y : p1y; \
    float e12 = hi ? B2.x : p2x, e13 = hi ? B2.y : p2y; \
    float e14 = hi ? B3.x : p3x, e15 = hi ? B3.y : p3y; \
    const float4* R = (const float4*)(AmT + ((size_t)((h * 4 + (TY)) * 16 + odb)) * 16); \
    _Pragma("unroll") \
    for (int oo = 0; oo < 8; ++oo) { \
      float4 r0 = R[oo*4+0], r1 = R[oo*4+1], r2 = R[oo*4+2], r3 = R[oo*4+3]; \
      out[oo] += r0.x*e0 + r0.y*e1 + r0.z*e2 + r0.w*e3 \
               + r1.x*e4 + r1.y*e5 + r1.z*e6 + r1.w*e7 \
               + r2.x*e8 + r2.y*e9 + r2.z*e10 + r2.w*e11 \
               + r3.x*e12 + r3.y*e13 + r3.z*e14 + r3.w*e15; \
    } }

    EPI(0, a00, a01, a02, a03)
    EPI(1, a10, a11, a12, a13)
    EPI(2, a20, a21, a22, a23)
    EPI(3, a30, a31, a32, a33)
#undef EPI

#pragma unroll
    for (int oo = 0; oo < 8; ++oo) out[oo] *= inv;
    ((uint4*)hbh)[(size_t)n * 16 + m] =
        make_uint4(bpack(out[0], out[1]), bpack(out[2], out[3]),
                   bpack(out[4], out[5]), bpack(out[6], out[7]));
  }
}

// ---- typed output projection via MFMA + sigmoid-skip residual ------------
__global__ __launch_bounds__(256) void k_out(const unsigned short* __restrict__ hbh,
                                             const unsigned short* __restrict__ WT,
                                             const float* __restrict__ skipv,
                                             float* __restrict__ xio,
                                             unsigned short* __restrict__ xh,
                                             int write_xh) {
  int ty, base, nrows;
  seg_decode64(blockIdx.x, ty, base, nrows);
  int w = threadIdx.x >> 6, l = threadIdx.x & 63;
  int r16 = l & 15, ks = l >> 4;
  int row0 = base + w * 16;
  int wrows = nrows - w * 16;

  bf16x8 a[4];
  const unsigned short* hrow = hbh + (size_t)(row0 + r16) * 128 + ks * 8;
#pragma unroll
  for (int kk = 0; kk < 4; ++kk) a[kk] = ld_frag(hrow + kk * 32);

  const unsigned short* WA = WT + (size_t)(3 * 3 + ty) * 16384;
  float alpha = 1.f / (1.f + __expf(-skipv[ty]));
  float beta = 1.f - alpha;

#pragma unroll 1
  for (int ct = 0; ct < 8; ++ct) {
    int o = ct * 16 + r16;
    const unsigned short* ba = WA + (size_t)o * 128 + ks * 8;
    f32x4 acc = {0.f,0.f,0.f,0.f};
#pragma unroll
    for (int kk = 0; kk < 4; ++kk)
      acc = __builtin_amdgcn_mfma_f32_16x16x32_bf16(a[kk], ld_frag(ba + kk * 32), acc, 0, 0, 0);
#pragma unroll
    for (int r = 0; r < 4; ++r) {
      int rrel = ks * 4 + r;
      size_t p = (size_t)(row0 + rrel) * 128 + o;
      float nx = 0.f;
      if (rrel < wrows) {
        nx = acc[r] * alpha + xio[p] * beta;
        xio[p] = nx;
      }
      float nxn = __shfl_xor(nx, 1);
      if (write_xh && rrel < wrows && (l & 1) == 0)
        ((unsigned*)xh)[p >> 1] = bpack(nx, nxn);
    }
  }
}

extern "C" void kernel_launch(void* const* d_in, const int* in_sizes, int n_in,
                              void* d_out, int out_size, void* d_ws, size_t ws_size,
                              hipStream_t stream) {
  const float* drug = (const float*)d_in[0];
  const float* dis  = (const float*)d_in[1];
  const float* prot = (const float*)d_in[2];
  const int* src    = (const int*)d_in[3];
  const int* dst    = (const int*)d_in[4];
  const int* etp    = (const int*)d_in[5];
  const float* Wk   = (const float*)d_in[6];
  const float* Wq   = (const float*)d_in[7];
  const float* Wv   = (const float*)d_in[8];
  const float* Wa   = (const float*)d_in[9];
  const float* rel_att = (const float*)d_in[10];
  const float* rel_msg = (const float*)d_in[11];
  const float* pri  = (const float*)d_in[12];
  const float* skip = (const float*)d_in[13];
  float* x = (float*)d_out;

  char* w = (char*)d_ws;
  uint2*          kvb = (uint2*)(w + 0);              // 25,600,000
  unsigned*       qbh = (unsigned*)(w + 25600000);    // 12,800,000
  unsigned*       hbh = (unsigned*)(w + 38400000);    // 12,800,000
  uint4*          qab = (uint4*)(w + 51200000);       // 51,200,000
  unsigned short* xh  = (unsigned short*)(w + 102400000); // 12,800,000
  unsigned short* WT  = (unsigned short*)(w + 115200000); //    393,216
  float*          AmT = (float*)(w + 115593216);      //     32,768
  int*            off = (int*)(w + 115625984);        //    200,004
  int*            est = (int*)(w + 115826048);        //  1,600,256
  // deg/cur alias hbh region (dead until first k_fused write)
  int*            deg = (int*)(w + 38400000);
  int*            cur = (int*)(w + 38600064);

  // x = concat(features), xh = bf16(x)
  k_concat<<<2048, 256, 0, stream>>>(drug, dis, prot, x, xh);

  // CSR by dst (edges constant across layers)
  (void)hipMemsetAsync(deg, 0, N_NODE * sizeof(int), stream);
  (void)hipMemsetAsync(est + N_EDGE, 0, 64 * sizeof(int), stream);
  k_count<<<(N_EDGE + 255) / 256, 256, 0, stream>>>(dst, deg);
  k_scan<<<1, 1024, 0, stream>>>(deg, off, cur);
  k_fill<<<(N_EDGE + 255) / 256, 256, 0, stream>>>(dst, src, etp, cur, est);

  // constant transforms
  k_trmsg<<<32, 256, 0, stream>>>(rel_msg, AmT);
  k_twt<<<768, 256, 0, stream>>>(Wk, Wq, Wv, Wa, WT);

  for (int layer = 0; layer < 2; ++layer) {
    k_qkv<<<MTILES, 256, 0, stream>>>(xh, WT, kvb, qbh);
    k_qa<<<QA_BLOCKS, 256, 0, stream>>>(qbh, rel_att, pri, qab);
    k_fused<<<FUSED_BLOCKS, 256, 0, stream>>>(kvb, qab, off, est, AmT, hbh);
    k_out<<<MTILES, 256, 0, stream>>>((const unsigned short*)hbh, WT, skip, x, xh,
                                      layer == 0 ? 1 : 0);
  }
}

// Round 11
// 848.161 us; speedup vs baseline: 1.8986x; 1.8986x over previous
//
#include <hip/hip_runtime.h>

#define N_NODE 50000
#define N_EDGE 400000
#define INF    128

#define FUSED_BLOCKS 1024   // 4 blocks/CU x 4 waves = 16 waves/CU at waves_per_eu(4,4)
#define QA_BLOCKS    1024

// 64-row MFMA tiles within type segments (boundaries 10000/20000 are 16-aligned)
#define MT0 157
#define MT1 157
#define MT2 469
#define MTILES 783

typedef __bf16 bf16x8 __attribute__((ext_vector_type(8)));
typedef float  f32x4  __attribute__((ext_vector_type(4)));

__device__ __forceinline__ void seg_decode64(int b, int& ty, int& base, int& nrows) {
  if (b < MT0)          { ty = 0; base = b * 64;                nrows = 10000 - base; }
  else if (b < MT0+MT1) { ty = 1; base = 10000 + (b - MT0)*64;  nrows = 20000 - base; }
  else                  { ty = 2; base = 20000 + (b-MT0-MT1)*64; nrows = 50000 - base; }
  if (nrows > 64) nrows = 64;
}

__device__ __forceinline__ float blo(unsigned u) { return __uint_as_float(u << 16); }
__device__ __forceinline__ float bhi(unsigned u) { return __uint_as_float(u & 0xffff0000u); }
// pack two f32 -> bf16x2 (RNE), lo = even dim, hi = odd dim
__device__ __forceinline__ unsigned bpack(float lo, float hi) {
  unsigned a = __float_as_uint(lo), b = __float_as_uint(hi);
  a = (a + 0x7fffu + ((a >> 16) & 1u)) >> 16;
  b = (b + 0x7fffu + ((b >> 16) & 1u)) & 0xffff0000u;
  return a | b;
}
__device__ __forceinline__ unsigned short b16(float v) {
  unsigned u = __float_as_uint(v);
  return (unsigned short)((u + 0x7fffu + ((u >> 16) & 1u)) >> 16);
}
__device__ __forceinline__ bf16x8 ld_frag(const unsigned short* p) {
  uint4 u = *reinterpret_cast<const uint4*>(p);
  return __builtin_bit_cast(bf16x8, u);
}

// ---- concat features into x (= d_out) + bf16 copy xh, grid-stride --------
__global__ __launch_bounds__(256) void k_concat(const float* __restrict__ dr,
                                                const float* __restrict__ di,
                                                const float* __restrict__ pr,
                                                float* __restrict__ x,
                                                unsigned short* __restrict__ xh) {
  for (int i = blockIdx.x * 256 + threadIdx.x; i < N_NODE * 32; i += 2048 * 256) {
    int row = i >> 5;
    float4 val;
    if (row < 10000)      val = ((const float4*)dr)[i];
    else if (row < 20000) val = ((const float4*)di)[i - 10000*32];
    else                  val = ((const float4*)pr)[i - 20000*32];
    ((float4*)x)[i] = val;
    ((uint2*)xh)[i] = make_uint2(bpack(val.x, val.y), bpack(val.z, val.w));
  }
}

// ---- CSR build -----------------------------------------------------------
__global__ __launch_bounds__(256) void k_count(const int* __restrict__ dst, int* __restrict__ deg) {
  int e = blockIdx.x * 256 + threadIdx.x;
  if (e < N_EDGE) atomicAdd(&deg[dst[e]], 1);
}

__global__ __launch_bounds__(1024) void k_scan(const int* __restrict__ deg,
                                               int* __restrict__ off, int* __restrict__ cur) {
  __shared__ int part[1024];
  int t = threadIdx.x;
  int c0 = t * 49;
  int c1 = c0 + 49; if (c1 > N_NODE) c1 = N_NODE;
  int s = 0;
  for (int i = c0; i < c1; ++i) s += deg[i];
  part[t] = s;
  __syncthreads();
  for (int ofs = 1; ofs < 1024; ofs <<= 1) {
    int v = (t >= ofs) ? part[t - ofs] : 0;
    __syncthreads();
    part[t] += v;
    __syncthreads();
  }
  int run = (t == 0) ? 0 : part[t - 1];
  for (int i = c0; i < c1; ++i) { off[i] = run; cur[i] = run; run += deg[i]; }
  if (t == 1023) off[N_NODE] = part[1023];
}

// writes combined edge record est[p] = (src<<2) | etype
__global__ __launch_bounds__(256) void k_fill(const int* __restrict__ dst,
                                              const int* __restrict__ src,
                                              const int* __restrict__ etp,
                                              int* __restrict__ cur, int* __restrict__ est) {
  int e = blockIdx.x * 256 + threadIdx.x;
  if (e < N_EDGE) {
    int p = atomicAdd(&cur[dst[e]], 1);
    est[p] = (src[e] << 2) | etp[e];
  }
}

// ---- transpose rel_msg: AmT[h][ty][do][di] = rel_msg[h][ty][di][do] ------
__global__ __launch_bounds__(256) void k_trmsg(const float* __restrict__ rm,
                                               float* __restrict__ AmT) {
  int i = blockIdx.x * 256 + threadIdx.x;   // 8192 total
  int di = i & 15, doo = (i >> 4) & 15, ty = (i >> 8) & 3, hh = i >> 10;
  AmT[i] = rm[((hh * 4 + ty) * 16 + di) * 16 + doo];
}

// ---- weight transpose to bf16: WT[(mat*3+ty)*16384 + o*128 + i] ----------
__global__ __launch_bounds__(256) void k_twt(const float* __restrict__ Wk,
                                             const float* __restrict__ Wq,
                                             const float* __restrict__ Wv,
                                             const float* __restrict__ Wa,
                                             unsigned short* __restrict__ WT) {
  int idx = blockIdx.x * 256 + threadIdx.x;
  if (idx >= 196608) return;
  int mt = idx >> 14;            // mat*3+ty
  int within = idx & 16383;
  int o = within >> 7, ii = within & 127;
  int mat = mt / 3, ty = mt % 3;
  const float* W = (mat == 0) ? Wk : (mat == 1) ? Wq : (mat == 2) ? Wv : Wa;
  WT[idx] = b16(W[ty * 16384 + ii * 128 + o]);
}

// ---- typed K/Q/V projection via MFMA; k,v packed interleaved bf16 --------
__global__ __launch_bounds__(256) void k_qkv(const unsigned short* __restrict__ xh,
                                             const unsigned short* __restrict__ WT,
                                             uint2* __restrict__ kvb,
                                             unsigned* __restrict__ qbh) {
  int ty, base, nrows;
  seg_decode64(blockIdx.x, ty, base, nrows);
  int w = threadIdx.x >> 6, l = threadIdx.x & 63;
  int r16 = l & 15, ks = l >> 4;
  int row0 = base + w * 16;
  int wrows = nrows - w * 16;        // valid rows in this wave's 16-row tile

  bf16x8 a[4];
  const unsigned short* xrow = xh + (size_t)(row0 + r16) * 128 + ks * 8;
#pragma unroll
  for (int kk = 0; kk < 4; ++kk) a[kk] = ld_frag(xrow + kk * 32);

  const unsigned short* WK = WT + (size_t)(0 * 3 + ty) * 16384;
  const unsigned short* WQ = WT + (size_t)(1 * 3 + ty) * 16384;
  const unsigned short* WV = WT + (size_t)(2 * 3 + ty) * 16384;

#pragma unroll 1
  for (int ct = 0; ct < 8; ++ct) {
    int o = ct * 16 + r16;
    const unsigned short* bk = WK + (size_t)o * 128 + ks * 8;
    const unsigned short* bq = WQ + (size_t)o * 128 + ks * 8;
    const unsigned short* bv = WV + (size_t)o * 128 + ks * 8;
    f32x4 ak = {0.f,0.f,0.f,0.f}, aq = {0.f,0.f,0.f,0.f}, av = {0.f,0.f,0.f,0.f};
#pragma unroll
    for (int kk = 0; kk < 4; ++kk) {
      bf16x8 fbk = ld_frag(bk + kk * 32);
      bf16x8 fbq = ld_frag(bq + kk * 32);
      bf16x8 fbv = ld_frag(bv + kk * 32);
      ak = __builtin_amdgcn_mfma_f32_16x16x32_bf16(a[kk], fbk, ak, 0, 0, 0);
      aq = __builtin_amdgcn_mfma_f32_16x16x32_bf16(a[kk], fbq, aq, 0, 0, 0);
      av = __builtin_amdgcn_mfma_f32_16x16x32_bf16(a[kk], fbv, av, 0, 0, 0);
    }
#pragma unroll
    for (int r = 0; r < 4; ++r) {
      int rrel = ks * 4 + r;
      float kn = __shfl_xor(ak[r], 1);
      float qn = __shfl_xor(aq[r], 1);
      float vn = __shfl_xor(av[r], 1);
      if (rrel < wrows && (l & 1) == 0) {
        size_t p = (size_t)(row0 + rrel);
        kvb[p * 64 + (o >> 1)] = make_uint2(bpack(ak[r], kn), bpack(av[r], vn));
        qbh[p * 64 + (o >> 1)] = bpack(aq[r], qn);
      }
    }
  }
}

// ---- qa precompute: qab[n][l] = 4-ty uint4 of (pri[h,ty]/4)*(A[h,ty].q[n]) --
__global__ __launch_bounds__(256) void k_qa(const unsigned* __restrict__ qbh,
                                            const float* __restrict__ rel_att,
                                            const float* __restrict__ pri,
                                            uint4* __restrict__ qab) {
  int w = threadIdx.x >> 6, l = threadIdx.x & 63;
  int h = l >> 3, j = l & 7;
  float4 prh = ((const float4*)pri)[h];
  float prs[4] = { prh.x * 0.25f, prh.y * 0.25f, prh.z * 0.25f, prh.w * 0.25f };
  for (int n = blockIdx.x * 4 + w; n < N_NODE; n += QA_BLOCKS * 4) {
    const uint4* qp = (const uint4*)qbh + (size_t)n * 16 + h * 2;
    uint4 u0 = qp[0], u1 = qp[1];
    float qf[16];
    qf[0]=blo(u0.x); qf[1]=bhi(u0.x); qf[2]=blo(u0.y); qf[3]=bhi(u0.y);
    qf[4]=blo(u0.z); qf[5]=bhi(u0.z); qf[6]=blo(u0.w); qf[7]=bhi(u0.w);
    qf[8]=blo(u1.x); qf[9]=bhi(u1.x); qf[10]=blo(u1.y); qf[11]=bhi(u1.y);
    qf[12]=blo(u1.z); qf[13]=bhi(u1.z); qf[14]=blo(u1.w); qf[15]=bhi(u1.w);
    unsigned pk[4];
#pragma unroll
    for (int ty = 0; ty < 4; ++ty) {
      const float* Ar = rel_att + (((h * 4 + ty) * 16) + 2 * j) * 16;
      float ax = 0.f, ay = 0.f;
#pragma unroll
      for (int o = 0; o < 16; ++o) {
        ax += Ar[o] * qf[o];
        ay += Ar[16 + o] * qf[o];
      }
      pk[ty] = bpack(ax * prs[ty], ay * prs[ty]);
    }
    qab[(size_t)n * 64 + l] = make_uint4(pk[0], pk[1], pk[2], pk[3]);
  }
}

// ---- fused attention: logits + edge-softmax + aggregation ---------------
// PERSISTENT: FUSED_BLOCKS x 4 waves, 1 wave per node (grid-stride).
// waves_per_eu(4,4): pins allocator at 128-VGPR budget -> no 64-VGPR spill
// collapse (R7-R10 lesson: WRITE_SIZE >> real output = scratch traffic).
__global__ __launch_bounds__(256)
__attribute__((amdgpu_waves_per_eu(4, 4)))
void k_fused(const uint2* __restrict__ kvb,
             const uint4* __restrict__ qab,
             const int* __restrict__ off,
             const int* __restrict__ est,
             const float* __restrict__ AmT,
             unsigned* __restrict__ hbh) {
  __shared__ float accs[4][4][128];
  int w = threadIdx.x >> 6, l = threadIdx.x & 63;
  int h = l >> 3, j = l & 7;

  for (int n = blockIdx.x * 4 + w; n < N_NODE; n += FUSED_BLOCKS * 4) {
    int o0 = off[n], o1 = off[n + 1];

    uint4 qu = qab[(size_t)n * 64 + l];
    float2 qa0 = make_float2(blo(qu.x), bhi(qu.x));
    float2 qa1 = make_float2(blo(qu.y), bhi(qu.y));
    float2 qa2 = make_float2(blo(qu.z), bhi(qu.z));
    float2 qa3 = make_float2(blo(qu.w), bhi(qu.w));

    float ssum = 0.f;
    float2 z = make_float2(0.f, 0.f);
    float2 at0 = z, at1 = z, at2 = z, at3 = z;

#define PROC(KV, TY, VALID) { \
    int ty = (TY) & 3; \
    float kx = blo((KV).x), ky = bhi((KV).x); \
    float2 qat = (ty==0)?qa0:(ty==1)?qa1:(ty==2)?qa2:qa3; \
    float part = kx*qat.x + ky*qat.y; \
    part += __shfl_xor(part, 1); \
    part += __shfl_xor(part, 2); \
    part += __shfl_xor(part, 4); \
    float wgt = (VALID) ? __expf(part) : 0.f; \
    ssum += wgt; \
    float vx = blo((KV).y), vy = bhi((KV).y); \
    float w0=(ty==0)?wgt:0.f, w1=(ty==1)?wgt:0.f, w2=(ty==2)?wgt:0.f, w3=(ty==3)?wgt:0.f; \
    at0.x += w0*vx; at0.y += w0*vy; \
    at1.x += w1*vx; at1.y += w1*vy; \
    at2.x += w2*vx; at2.y += w2*vy; \
    at3.x += w3*vx; at3.y += w3*vy; }

    for (int b0 = o0; b0 < o1; b0 += 64) {
      int cnt = o1 - b0; if (cnt > 64) cnt = 64;
      int stv = est[b0 + l];          // est padded by 64 -> no guard needed
      int t0 = __shfl(stv, 0);
      int t1 = __shfl(stv, 1 < cnt ? 1 : 0);
      uint2 kv0 = kvb[(size_t)(t0 >> 2) * 64 + l];
      uint2 kv1 = kvb[(size_t)(t1 >> 2) * 64 + l];
      for (int i = 0; i < cnt; i += 2) {
        bool more = (i + 2) < cnt;        // wave-uniform
        int n0 = 0, n1 = 0; uint2 kn0, kn1;
        if (more) {
          n0 = __shfl(stv, i + 2);
          n1 = __shfl(stv, (i + 3) < cnt ? (i + 3) : (i + 2));
          kn0 = kvb[(size_t)(n0 >> 2) * 64 + l];
          kn1 = kvb[(size_t)(n1 >> 2) * 64 + l];
        }
        PROC(kv0, t0, true)
        PROC(kv1, t1, (i + 1) < cnt)
        if (more) { t0 = n0; t1 = n1; kv0 = kn0; kv1 = kn1; }
      }
    }
#undef PROC

    float inv = (ssum > 0.f) ? 1.f / ssum : 0.f;
    at0.x *= inv; at0.y *= inv;
    at1.x *= inv; at1.y *= inv;
    at2.x *= inv; at2.y *= inv;
    at3.x *= inv; at3.y *= inv;

    ((float2*)&accs[w][0][0])[l] = at0;
    ((float2*)&accs[w][1][0])[l] = at1;
    ((float2*)&accs[w][2][0])[l] = at2;
    ((float2*)&accs[w][3][0])[l] = at3;

    float ox = 0.f, oy = 0.f;
#pragma unroll
    for (int ty = 0; ty < 4; ++ty) {
      const float4* AmR = (const float4*)(AmT + ((h * 4 + ty) * 16) * 16);
#pragma unroll
      for (int d4 = 0; d4 < 4; ++d4) {
        float4 ac = *((float4*)&accs[w][ty][h * 16 + d4 * 4]);
        float4 m0 = AmR[(2 * j) * 4 + d4];
        float4 m1 = AmR[(2 * j + 1) * 4 + d4];
        ox += m0.x * ac.x + m0.y * ac.y + m0.z * ac.z + m0.w * ac.w;
        oy += m1.x * ac.x + m1.y * ac.y + m1.z * ac.z + m1.w * ac.w;
      }
    }
    hbh[(size_t)n * 64 + l] = bpack(ox, oy);   // dims (2l, 2l+1)
  }
}

// ---- typed output projection via MFMA + sigmoid-skip residual ------------
__global__ __launch_bounds__(256) void k_out(const unsigned short* __restrict__ hbh,
                                             const unsigned short* __restrict__ WT,
                                             const float* __restrict__ skipv,
                                             float* __restrict__ xio,
                                             unsigned short* __restrict__ xh,
                                             int write_xh) {
  int ty, base, nrows;
  seg_decode64(blockIdx.x, ty, base, nrows);
  int w = threadIdx.x >> 6, l = threadIdx.x & 63;
  int r16 = l & 15, ks = l >> 4;
  int row0 = base + w * 16;
  int wrows = nrows - w * 16;

  bf16x8 a[4];
  const unsigned short* hrow = hbh + (size_t)(row0 + r16) * 128 + ks * 8;
#pragma unroll
  for (int kk = 0; kk < 4; ++kk) a[kk] = ld_frag(hrow + kk * 32);

  const unsigned short* WA = WT + (size_t)(3 * 3 + ty) * 16384;
  float alpha = 1.f / (1.f + __expf(-skipv[ty]));
  float beta = 1.f - alpha;

#pragma unroll 1
  for (int ct = 0; ct < 8; ++ct) {
    int o = ct * 16 + r16;
    const unsigned short* ba = WA + (size_t)o * 128 + ks * 8;
    f32x4 acc = {0.f,0.f,0.f,0.f};
#pragma unroll
    for (int kk = 0; kk < 4; ++kk)
      acc = __builtin_amdgcn_mfma_f32_16x16x32_bf16(a[kk], ld_frag(ba + kk * 32), acc, 0, 0, 0);
#pragma unroll
    for (int r = 0; r < 4; ++r) {
      int rrel = ks * 4 + r;
      size_t p = (size_t)(row0 + rrel) * 128 + o;
      float nx = 0.f;
      if (rrel < wrows) {
        nx = acc[r] * alpha + xio[p] * beta;
        xio[p] = nx;
      }
      float nxn = __shfl_xor(nx, 1);
      if (write_xh && rrel < wrows && (l & 1) == 0)
        ((unsigned*)xh)[p >> 1] = bpack(nx, nxn);
    }
  }
}

extern "C" void kernel_launch(void* const* d_in, const int* in_sizes, int n_in,
                              void* d_out, int out_size, void* d_ws, size_t ws_size,
                              hipStream_t stream) {
  const float* drug = (const float*)d_in[0];
  const float* dis  = (const float*)d_in[1];
  const float* prot = (const float*)d_in[2];
  const int* src    = (const int*)d_in[3];
  const int* dst    = (const int*)d_in[4];
  const int* etp    = (const int*)d_in[5];
  const float* Wk   = (const float*)d_in[6];
  const float* Wq   = (const float*)d_in[7];
  const float* Wv   = (const float*)d_in[8];
  const float* Wa   = (const float*)d_in[9];
  const float* rel_att = (const float*)d_in[10];
  const float* rel_msg = (const float*)d_in[11];
  const float* pri  = (const float*)d_in[12];
  const float* skip = (const float*)d_in[13];
  float* x = (float*)d_out;

  char* w = (char*)d_ws;
  uint2*          kvb = (uint2*)(w + 0);              // 25,600,000
  unsigned*       qbh = (unsigned*)(w + 25600000);    // 12,800,000
  unsigned*       hbh = (unsigned*)(w + 38400000);    // 12,800,000
  uint4*          qab = (uint4*)(w + 51200000);       // 51,200,000
  unsigned short* xh  = (unsigned short*)(w + 102400000); // 12,800,000
  unsigned short* WT  = (unsigned short*)(w + 115200000); //    393,216
  float*          AmT = (float*)(w + 115593216);      //     32,768
  int*            off = (int*)(w + 115625984);        //    200,004
  int*            est = (int*)(w + 115826048);        //  1,600,256
  // deg/cur alias hbh region (dead until first k_fused write)
  int*            deg = (int*)(w + 38400000);
  int*            cur = (int*)(w + 38600064);

  // x = concat(features), xh = bf16(x)
  k_concat<<<2048, 256, 0, stream>>>(drug, dis, prot, x, xh);

  // CSR by dst (edges constant across layers)
  (void)hipMemsetAsync(deg, 0, N_NODE * sizeof(int), stream);
  (void)hipMemsetAsync(est + N_EDGE, 0, 64 * sizeof(int), stream);
  k_count<<<(N_EDGE + 255) / 256, 256, 0, stream>>>(dst, deg);
  k_scan<<<1, 1024, 0, stream>>>(deg, off, cur);
  k_fill<<<(N_EDGE + 255) / 256, 256, 0, stream>>>(dst, src, etp, cur, est);

  // constant transforms
  k_trmsg<<<32, 256, 0, stream>>>(rel_msg, AmT);
  k_twt<<<768, 256, 0, stream>>>(Wk, Wq, Wv, Wa, WT);

  for (int layer = 0; layer < 2; ++layer) {
    k_qkv<<<MTILES, 256, 0, stream>>>(xh, WT, kvb, qbh);
    k_qa<<<QA_BLOCKS, 256, 0, stream>>>(qbh, rel_att, pri, qab);
    k_fused<<<FUSED_BLOCKS, 256, 0, stream>>>(kvb, qab, off, est, AmT, hbh);
    k_out<<<MTILES, 256, 0, stream>>>((const unsigned short*)hbh, WT, skip, x, xh,
                                      layer == 0 ? 1 : 0);
  }
}